// Round 20
// baseline (355.266 us; speedup 1.0000x reference)
//
#include <hip/hip_runtime.h>
#include <hip/hip_bf16.h>

#define NTOK 2048   // B*S
#define HD   1024
#define FD   3584
#define NE   8

#define BM 128              // gemm1 m-tile
#define BN1 64              // gemm1 f-tile
#define BM2 64              // gemm2 m-tile
#define BN 128              // gemm2 h-tile
#define BK 64
#define NIT1 (HD / BK)      // 16
#define KS2 2               // gemm2 K-split
#define KLEN2 (FD / KS2)    // 1792
#define NIT2 (KLEN2 / BK)   // 28

typedef __attribute__((ext_vector_type(8))) short short8;
typedef __attribute__((ext_vector_type(4))) float f32x4;

__device__ __forceinline__ unsigned short f2bf(float f) {
    __hip_bfloat16 h = __float2bfloat16(f);
    union { __hip_bfloat16 h; unsigned short u; } c; c.h = h;
    return c.u;
}

// global_load_lds width=16: per-lane 16B global src -> wave-uniform LDS base + lane*16
typedef __attribute__((address_space(1))) const unsigned int g_cu32;
typedef __attribute__((address_space(3))) unsigned int l_u32;
__device__ __forceinline__ void gl16(const void* g, void* l) {
    __builtin_amdgcn_global_load_lds((g_cu32*)g, (l_u32*)(unsigned int)(size_t)l, 16, 0, 0);
}

// read one bf16 k-octet fragment from the pair layout P[n][32 words]:
// word = n*32 + 4*((q ^ (n>>3)) & 7)   (k_wt3 phase-B pattern, measured 0-conflict;
// bijectivity of the pair-XOR layout was numerically validated by r18's absmax)
__device__ __forceinline__ short8 pfrag(const unsigned int* P, int n, int q) {
    uint4 v = *(const uint4*)&P[n * 32 + 4 * ((q ^ (n >> 3)) & 7)];
    union { uint4 u; short8 s; } c; c.u = v;
    return c.s;
}

// ---------------- router: fp32 logits, softmax, top-2, renorm ----------------
__global__ void k_router(const float* __restrict__ x, const float* __restrict__ gw,
                         int* __restrict__ sel, float* __restrict__ selw,
                         int* __restrict__ counts) {
    int token = blockIdx.x * 4 + (threadIdx.x >> 6);
    int lane  = threadIdx.x & 63;
    if (token >= NTOK) return;
    const float* xr = x + (size_t)token * HD;
    float acc[NE];
#pragma unroll
    for (int e = 0; e < NE; e++) acc[e] = 0.f;
    for (int h = lane; h < HD; h += 64) {
        float xv = xr[h];
        const float4* g = (const float4*)(gw + (size_t)h * NE);
        float4 g0 = g[0], g1 = g[1];
        acc[0] += xv * g0.x; acc[1] += xv * g0.y; acc[2] += xv * g0.z; acc[3] += xv * g0.w;
        acc[4] += xv * g1.x; acc[5] += xv * g1.y; acc[6] += xv * g1.z; acc[7] += xv * g1.w;
    }
#pragma unroll
    for (int e = 0; e < NE; e++) {
#pragma unroll
        for (int off = 32; off >= 1; off >>= 1) acc[e] += __shfl_xor(acc[e], off, 64);
    }
    if (lane == 0) {
        float m = acc[0];
#pragma unroll
        for (int e = 1; e < NE; e++) m = fmaxf(m, acc[e]);
        float z[NE];
#pragma unroll
        for (int e = 0; e < NE; e++) z[e] = expf(acc[e] - m);
        int e0 = 0; float z0 = z[0];
#pragma unroll
        for (int e = 1; e < NE; e++) if (z[e] > z0) { z0 = z[e]; e0 = e; }
        int e1 = -1; float z1 = -1.f;
#pragma unroll
        for (int e = 0; e < NE; e++) if (e != e0 && z[e] > z1) { z1 = z[e]; e1 = e; }
        float s = z0 + z1;
        sel[token * 2 + 0] = e0; sel[token * 2 + 1] = e1;
        selw[token * 2 + 0] = z0 / s; selw[token * 2 + 1] = z1 / s;
        atomicAdd(&counts[e0], 1);
        atomicAdd(&counts[e1], 1);
    }
}

__global__ void k_scan(const int* __restrict__ counts, int* __restrict__ basep,
                       int* __restrict__ fillc) {
    if (threadIdx.x == 0 && blockIdx.x == 0) {
        int b = 0;
        for (int e = 0; e < NE; e++) { basep[e] = b; b += counts[e]; fillc[e] = 0; }
    }
}

__global__ void k_fill(const int* __restrict__ sel, const float* __restrict__ selw,
                       const int* __restrict__ basep, int* __restrict__ fillc,
                       int* __restrict__ rowmap, int* __restrict__ rowk,
                       float* __restrict__ roww) {
    int n = blockIdx.x * blockDim.x + threadIdx.x;
    if (n >= NTOK) return;
#pragma unroll
    for (int k = 0; k < 2; k++) {
        int e = sel[n * 2 + k];
        int p = atomicAdd(&fillc[e], 1);
        int g = basep[e] + p;
        rowmap[g] = n; rowk[g] = k; roww[g] = selw[n * 2 + k];
    }
}

// ---------------- x -> bf16 ----------------
__global__ void k_cvt(const float* __restrict__ x, unsigned short* __restrict__ xb) {
    size_t i = ((size_t)blockIdx.x * blockDim.x + threadIdx.x) * 8;
    float4 a = *(const float4*)(x + i);
    float4 b = *(const float4*)(x + i + 4);
    unsigned short p[8] __attribute__((aligned(16))) =
        { f2bf(a.x), f2bf(a.y), f2bf(a.z), f2bf(a.w),
          f2bf(b.x), f2bf(b.y), f2bf(b.z), f2bf(b.w) };
    *(uint4*)(xb + i) = *(uint4*)p;
}

// ---------------- GEMM1: direct fp32 w1/w3, pair-layout LDS (no transpose pass) ----------------
// A: xb bf16 via gl16 (r18 path, unchanged).
// B: per matrix (half=t>>7), 128 threads stage a 64k x 64n fp32 tile into pair
// layout P[n][32]: thread (rp=(t&127)>>2, c4=t&3) loads k-rows {2rp,2rp+1} x
// 16 cols (8 float4 loads/tile/thread), packs k-pairs, 16x ds_write_b32 at
// P[n*32 + (rp ^ (((n>>3)&7)<<2))] (k_wt3 phase-A pattern, 0 conflicts).
// MFMA fragments read DIRECTLY from P via pfrag (k_wt3 phase-B, 0 conflicts).
// vmcnt(8): outstanding at the wait = 4 A-gloads (oldest) + 8 B-loads (newest);
// drains exactly the A-gloads, keeps all 8 B loads in flight.
// (r19 BUG: vmcnt(16) with only 12 outstanding = no-op -> At race -> NaN.)
__global__ __launch_bounds__(256, 2) void k_gemm1(
    const unsigned short* __restrict__ xb,
    const float* __restrict__ w1, const float* __restrict__ w3,
    const int* __restrict__ counts, const int* __restrict__ basep,
    const int* __restrict__ rowmap, unsigned short* __restrict__ act)
{
    const int e = blockIdx.z;
    const int nrows = counts[e];
    const int m0 = blockIdx.y * BM;
    if (m0 >= nrows) return;
    const int f0 = blockIdx.x * BN1;
    const int gbase = basep[e];

    __shared__ __align__(16) unsigned short At[2][BM][BK];
    __shared__ __align__(16) unsigned int P1[2][BN1 * 32];
    __shared__ __align__(16) unsigned int P3[2][BN1 * 32];

    const int t = threadIdx.x;
    const int lane = t & 63;
    const int w = t >> 6;                 // 0..3
    const int wrm = w >> 1, wnn = w & 1;  // 2x2 wave grid; wave tile 64 x 32
    const int lr = lane >> 3;
    const int so = ((lane & 7) ^ lr) * 8; // A staging pre-swizzle (verified)

    const unsigned short* asrc[4];
#pragma unroll
    for (int c = 0; c < 4; c++) {
        const int row = (w * 4 + c) * 8 + lr;
        const int tok = rowmap[gbase + min(m0 + row, nrows - 1)];
        asrc[c] = xb + (size_t)tok * HD + so;
    }

    // B staging mapping (per matrix half)
    const int th = t & 127;
    const int rp = th >> 2;               // k-pair row 0..31
    const int c4 = th & 3;                // 16-col group
    const int half = t >> 7;
    const float* bp = (half ? w3 : w1) + (size_t)e * HD * FD
                    + (size_t)(2 * rp) * FD + f0 + c4 * 16;
    unsigned int* const myP = half ? &P3[0][0] : &P1[0][0];
    const int PB = BN1 * 32;              // words per buffer

    f32x4 acc1[4][2], acc3[4][2];
#pragma unroll
    for (int i = 0; i < 4; i++)
#pragma unroll
        for (int j = 0; j < 2; j++) { acc1[i][j] = (f32x4)(0.f); acc3[i][j] = (f32x4)(0.f); }

    const int l15 = lane & 15;
    const int lhi = lane >> 4;
    const int rs = (l15 & 7) * 8;

    float4 bv0[4], bv1[4];                // rows 2rp, 2rp+1 x 16 cols

#define G1_LOADB(koff_) do {                                                    \
    _Pragma("unroll")                                                           \
    for (int m = 0; m < 4; m++) {                                               \
        bv0[m] = *(const float4*)(bp + (size_t)(koff_) * FD + 4 * m);           \
        bv1[m] = *(const float4*)(bp + (size_t)((koff_) + 1) * FD + 4 * m);     \
    }                                                                           \
} while (0)

#define G1_WRITEB(buf_) do {                                                    \
    _Pragma("unroll")                                                           \
    for (int m = 0; m < 4; m++) {                                               \
        _Pragma("unroll")                                                       \
        for (int q = 0; q < 4; q++) {                                           \
            const int n = c4 * 16 + 4 * m + q;                                  \
            unsigned int v = (unsigned int)f2bf(((const float*)&bv0[m])[q])     \
                           | ((unsigned int)f2bf(((const float*)&bv1[m])[q]) << 16); \
            myP[(buf_) * PB + n * 32 + (rp ^ (((n >> 3) & 7) << 2))] = v;       \
        }                                                                       \
    }                                                                           \
} while (0)

    // prologue
    G1_LOADB(0);
    G1_WRITEB(0);                          // auto vmcnt wait on bv
#pragma unroll
    for (int c = 0; c < 4; c++) gl16(asrc[c], &At[0][(w * 4 + c) * 8][0]);
    if (NIT1 > 1) G1_LOADB(BK);            // B(1): 8 loads in flight
    asm volatile("s_waitcnt lgkmcnt(0)" ::: "memory");
    asm volatile("s_waitcnt vmcnt(8)" ::: "memory");    // drain 4 A-gloads only
    __builtin_amdgcn_s_barrier();

    for (int it = 0; it < NIT1; ++it) {
        const int cur = it & 1;
        const bool more = (it + 1 < NIT1);
        const bool more2 = (it + 2 < NIT1);
        if (more) {
#pragma unroll
            for (int c = 0; c < 4; c++)
                gl16(asrc[c] + (size_t)(it + 1) * BK, &At[cur ^ 1][(w * 4 + c) * 8][0]);
            G1_WRITEB(cur ^ 1);            // waits bv (oldest), leaves A in flight
            if (more2) G1_LOADB((size_t)(it + 2) * BK);
        }
#pragma unroll
        for (int kk = 0; kk < 2; kk++) {
            const int kc = (kk * 32 + lhi * 8) ^ rs;
            const int q = kk * 4 + lhi;
            short8 af[4], b1f[2], b3f[2];
#pragma unroll
            for (int i = 0; i < 4; i++)
                af[i] = *(const short8*)&At[cur][wrm * 64 + i * 16 + l15][kc];
#pragma unroll
            for (int j = 0; j < 2; j++) {
                const int n = wnn * 32 + j * 16 + l15;
                b1f[j] = pfrag(&P1[cur][0], n, q);
                b3f[j] = pfrag(&P3[cur][0], n, q);
            }
#pragma unroll
            for (int i = 0; i < 4; i++)
#pragma unroll
                for (int j = 0; j < 2; j++) {
                    acc1[i][j] = __builtin_amdgcn_mfma_f32_16x16x32_bf16(af[i], b1f[j], acc1[i][j], 0, 0, 0);
                    acc3[i][j] = __builtin_amdgcn_mfma_f32_16x16x32_bf16(af[i], b3f[j], acc3[i][j], 0, 0, 0);
                }
        }
        if (more) {
            asm volatile("s_waitcnt lgkmcnt(0)" ::: "memory");   // P writes done
            if (more2) asm volatile("s_waitcnt vmcnt(8)" ::: "memory");  // drain A only
            else       asm volatile("s_waitcnt vmcnt(0)" ::: "memory");
        }
        __builtin_amdgcn_s_barrier();
    }

    // epilogue: SwiGLU, bf16 act
    const int rbase = wrm * 64 + lhi * 4;
    const int cbase = f0 + wnn * 32 + l15;
#pragma unroll
    for (int i = 0; i < 4; i++) {
#pragma unroll
        for (int r = 0; r < 4; r++) {
            const int ml = rbase + i * 16 + r;
            if (m0 + ml < nrows) {
                const size_t rowoff = (size_t)(gbase + m0 + ml) * FD;
#pragma unroll
                for (int j = 0; j < 2; j++) {
                    float y1 = acc1[i][j][r];
                    float y3 = acc3[i][j][r];
                    float sv = (y1 / (1.f + __expf(-y1))) * y3;
                    act[rowoff + cbase + j * 16] = f2bf(sv);
                }
            }
        }
    }
#undef G1_LOADB
#undef G1_WRITEB
}

// ---------------- GEMM2: direct fp32 w2, pair-layout LDS; K-split x2, atomic out ----------------
// B tile: 64k x 128n. 256 threads: rp=t>>3 (0..31), c8=t&7 (16-col group).
// P[128n][32]: 16KB/buf. vmcnt(8) drains the 2 A-gloads (oldest), keeps 8 B loads.
__global__ __launch_bounds__(256, 3) void k_gemm2(
    const unsigned short* __restrict__ act,
    const float* __restrict__ w2,
    const int* __restrict__ counts, const int* __restrict__ basep,
    const int* __restrict__ rowmap, const int* __restrict__ rowk,
    const float* __restrict__ roww, float* __restrict__ out)
{
    const int z = blockIdx.z;
    const int e = z >> 1, ks = z & 1;
    const int nrows = counts[e];
    const int m0 = blockIdx.y * BM2;
    if (m0 >= nrows) return;
    const int h0 = blockIdx.x * BN;
    const int gbase = basep[e];
    const int kbase = ks * KLEN2;

    __shared__ __align__(16) unsigned short At[2][BM2][BK];
    __shared__ __align__(16) unsigned int P[2][BN * 32];

    const int t = threadIdx.x;
    const int lane = t & 63;
    const int w = t >> 6;                 // 0..3
    const int wr2 = w >> 1, wn2 = w & 1;  // 2x2; wave tile 32 x 64
    const int lr = lane >> 3;
    const int so = ((lane & 7) ^ lr) * 8;

    const unsigned short* asrc[2];
#pragma unroll
    for (int c = 0; c < 2; c++) {
        const int row = (w * 2 + c) * 8 + lr;
        asrc[c] = act + ((size_t)gbase + min(m0 + row, nrows - 1)) * FD + so + kbase;
    }

    const int rp = t >> 3;                // k-pair row 0..31
    const int c8 = t & 7;                 // 16-col group 0..7
    const float* bp = w2 + (size_t)e * FD * HD + (size_t)(kbase + 2 * rp) * HD + h0 + c8 * 16;

    f32x4 acc[2][4];
#pragma unroll
    for (int i = 0; i < 2; i++)
#pragma unroll
        for (int j = 0; j < 4; j++) acc[i][j] = (f32x4)(0.f);

    const int l15 = lane & 15;
    const int lhi = lane >> 4;
    const int rs = (l15 & 7) * 8;

    float4 bv0[4], bv1[4];

#define G2_LOADB(koff_) do {                                                    \
    _Pragma("unroll")                                                           \
    for (int m = 0; m < 4; m++) {                                               \
        bv0[m] = *(const float4*)(bp + (size_t)(koff_) * HD + 4 * m);           \
        bv1[m] = *(const float4*)(bp + (size_t)((koff_) + 1) * HD + 4 * m);     \
    }                                                                           \
} while (0)

#define G2_WRITEB(buf_) do {                                                    \
    _Pragma("unroll")                                                           \
    for (int m = 0; m < 4; m++) {                                               \
        _Pragma("unroll")                                                       \
        for (int q = 0; q < 4; q++) {                                           \
            const int n = c8 * 16 + 4 * m + q;                                  \
            unsigned int v = (unsigned int)f2bf(((const float*)&bv0[m])[q])     \
                           | ((unsigned int)f2bf(((const float*)&bv1[m])[q]) << 16); \
            P[buf_][n * 32 + (rp ^ (((n >> 3) & 7) << 2))] = v;                 \
        }                                                                       \
    }                                                                           \
} while (0)

    // prologue
    G2_LOADB(0);
    G2_WRITEB(0);
#pragma unroll
    for (int c = 0; c < 2; c++) gl16(asrc[c], &At[0][(w * 2 + c) * 8][0]);
    if (NIT2 > 1) G2_LOADB(BK);
    asm volatile("s_waitcnt lgkmcnt(0)" ::: "memory");
    asm volatile("s_waitcnt vmcnt(8)" ::: "memory");    // drain 2 A-gloads only
    __builtin_amdgcn_s_barrier();

    for (int it = 0; it < NIT2; ++it) {
        const int cur = it & 1;
        const bool more = (it + 1 < NIT2);
        const bool more2 = (it + 2 < NIT2);
        if (more) {
#pragma unroll
            for (int c = 0; c < 2; c++)
                gl16(asrc[c] + (size_t)(it + 1) * BK, &At[cur ^ 1][(w * 2 + c) * 8][0]);
            G2_WRITEB(cur ^ 1);
            if (more2) G2_LOADB((size_t)(it + 2) * BK);
        }
#pragma unroll
        for (int kk = 0; kk < 2; kk++) {
            const int kc = (kk * 32 + lhi * 8) ^ rs;
            const int q = kk * 4 + lhi;
            short8 af[2], bf[4];
#pragma unroll
            for (int i = 0; i < 2; i++)
                af[i] = *(const short8*)&At[cur][wr2 * 32 + i * 16 + l15][kc];
#pragma unroll
            for (int j = 0; j < 4; j++) {
                const int n = wn2 * 64 + j * 16 + l15;
                bf[j] = pfrag(&P[cur][0], n, q);
            }
#pragma unroll
            for (int i = 0; i < 2; i++)
#pragma unroll
                for (int j = 0; j < 4; j++)
                    acc[i][j] = __builtin_amdgcn_mfma_f32_16x16x32_bf16(af[i], bf[j], acc[i][j], 0, 0, 0);
        }
        if (more) {
            asm volatile("s_waitcnt lgkmcnt(0)" ::: "memory");
            if (more2) asm volatile("s_waitcnt vmcnt(8)" ::: "memory");
            else       asm volatile("s_waitcnt vmcnt(0)" ::: "memory");
        }
        __builtin_amdgcn_s_barrier();
    }

    const int rbase = wr2 * 32 + lhi * 4;
    const int cbase = h0 + wn2 * 64 + l15;
#pragma unroll
    for (int i = 0; i < 2; i++) {
#pragma unroll
        for (int r = 0; r < 4; r++) {
            const int ml = rbase + i * 16 + r;
            if (m0 + ml < nrows) {
                const int grow = gbase + m0 + ml;
                const int tok = rowmap[grow];
                const float wv = roww[grow];
                float* op = out + (size_t)tok * HD + cbase;
#pragma unroll
                for (int j = 0; j < 4; j++)
                    atomicAdd(&op[j * 16], acc[i][j][r] * wv);
            }
        }
    }
#undef G2_LOADB
#undef G2_WRITEB
}

extern "C" void kernel_launch(void* const* d_in, const int* in_sizes, int n_in,
                              void* d_out, int out_size, void* d_ws, size_t ws_size,
                              hipStream_t stream) {
    const float* x  = (const float*)d_in[0];
    const float* gw = (const float*)d_in[1];
    const float* w1 = (const float*)d_in[2];
    const float* w3 = (const float*)d_in[3];
    const float* w2 = (const float*)d_in[4];
    float* out = (float*)d_out;

    char* ws = (char*)d_ws;
    size_t off = 0;
    auto alloc = [&](size_t b) { char* p = ws + off; off += (b + 255) & ~(size_t)255; return p; };
    int*   sel    = (int*)  alloc((size_t)NTOK * 2 * 4);
    float* selw   = (float*)alloc((size_t)NTOK * 2 * 4);
    int*   counts = (int*)  alloc(NE * 4);
    int*   basep  = (int*)  alloc(NE * 4);
    int*   fillc  = (int*)  alloc(NE * 4);
    int*   rowmap = (int*)  alloc((size_t)NTOK * 2 * 4);
    int*   rowk   = (int*)  alloc((size_t)NTOK * 2 * 4);
    float* roww   = (float*)alloc((size_t)NTOK * 2 * 4);
    unsigned short* xb  = (unsigned short*)alloc((size_t)NTOK * HD * 2);
    unsigned short* act = (unsigned short*)alloc((size_t)NTOK * 2 * FD * 2);

    hipMemsetAsync(counts, 0, NE * 4, stream);
    hipMemsetAsync(out, 0, (size_t)out_size * 4, stream);   // gemm2 accumulates atomically
    k_cvt<<<(NTOK * HD) / (256 * 8), 256, 0, stream>>>(x, xb);
    k_router<<<NTOK / 4, 256, 0, stream>>>(x, gw, sel, selw, counts);
    k_scan<<<1, 64, 0, stream>>>(counts, basep, fillc);
    k_fill<<<NTOK / 256, 256, 0, stream>>>(sel, selw, basep, fillc, rowmap, rowk, roww);
    k_gemm1<<<dim3(FD / BN1, NTOK / BM, NE), 256, 0, stream>>>(xb, w1, w3, counts, basep, rowmap, act);
    k_gemm2<<<dim3(HD / BN, NTOK / BM2, NE * KS2), 256, 0, stream>>>(act, w2, counts, basep, rowmap, rowk, roww, out);
}

// Round 21
// 318.176 us; speedup vs baseline: 1.1166x; 1.1166x over previous
//
#include <hip/hip_runtime.h>
#include <hip/hip_bf16.h>

#define NTOK 2048   // B*S
#define HD   1024
#define FD   3584
#define NE   8

#define BM 128              // gemm1 m-tile
#define BN1 64              // gemm1 f-tile
#define BM2 64              // gemm2 m-tile
#define BN 128              // gemm2 h-tile
#define BK 64               // 128B LDS rows (verified conflict-free layout)
#define NIT1 (HD / BK)      // 16
#define KS2 2               // gemm2 K-split
#define KLEN2 (FD / KS2)    // 1792
#define NIT2 (KLEN2 / BK)   // 28
#define TSZ 4096            // shorts per 64x64 weight tile (8KB)

typedef __attribute__((ext_vector_type(8))) short short8;
typedef __attribute__((ext_vector_type(4))) float f32x4;

__device__ __forceinline__ unsigned short f2bf(float f) {
    __hip_bfloat16 h = __float2bfloat16(f);
    union { __hip_bfloat16 h; unsigned short u; } c; c.h = h;
    return c.u;
}

// global_load_lds width=16: per-lane 16B global src -> wave-uniform LDS base + lane*16
typedef __attribute__((address_space(1))) const unsigned int g_cu32;
typedef __attribute__((address_space(3))) unsigned int l_u32;
__device__ __forceinline__ void gl16(const void* g, void* l) {
    __builtin_amdgcn_global_load_lds((g_cu32*)g, (l_u32*)(unsigned int)(size_t)l, 16, 0, 0);
}

// ---------------- router: fp32 logits, softmax, top-2, renorm ----------------
__global__ void k_router(const float* __restrict__ x, const float* __restrict__ gw,
                         int* __restrict__ sel, float* __restrict__ selw,
                         int* __restrict__ counts) {
    int token = blockIdx.x * 4 + (threadIdx.x >> 6);
    int lane  = threadIdx.x & 63;
    if (token >= NTOK) return;
    const float* xr = x + (size_t)token * HD;
    float acc[NE];
#pragma unroll
    for (int e = 0; e < NE; e++) acc[e] = 0.f;
    for (int h = lane; h < HD; h += 64) {
        float xv = xr[h];
        const float4* g = (const float4*)(gw + (size_t)h * NE);
        float4 g0 = g[0], g1 = g[1];
        acc[0] += xv * g0.x; acc[1] += xv * g0.y; acc[2] += xv * g0.z; acc[3] += xv * g0.w;
        acc[4] += xv * g1.x; acc[5] += xv * g1.y; acc[6] += xv * g1.z; acc[7] += xv * g1.w;
    }
#pragma unroll
    for (int e = 0; e < NE; e++) {
#pragma unroll
        for (int off = 32; off >= 1; off >>= 1) acc[e] += __shfl_xor(acc[e], off, 64);
    }
    if (lane == 0) {
        float m = acc[0];
#pragma unroll
        for (int e = 1; e < NE; e++) m = fmaxf(m, acc[e]);
        float z[NE];
#pragma unroll
        for (int e = 0; e < NE; e++) z[e] = expf(acc[e] - m);
        int e0 = 0; float z0 = z[0];
#pragma unroll
        for (int e = 1; e < NE; e++) if (z[e] > z0) { z0 = z[e]; e0 = e; }
        int e1 = -1; float z1 = -1.f;
#pragma unroll
        for (int e = 0; e < NE; e++) if (e != e0 && z[e] > z1) { z1 = z[e]; e1 = e; }
        float s = z0 + z1;
        sel[token * 2 + 0] = e0; sel[token * 2 + 1] = e1;
        selw[token * 2 + 0] = z0 / s; selw[token * 2 + 1] = z1 / s;
        atomicAdd(&counts[e0], 1);
        atomicAdd(&counts[e1], 1);
    }
}

// ---------------- fused scan+fill: 1 block; scan in LDS, grid-stride fill ----------------
__global__ void k_scanfill(const int* __restrict__ counts, const int* __restrict__ sel,
                           const float* __restrict__ selw, int* __restrict__ basep,
                           int* __restrict__ rowmap, int* __restrict__ rowk,
                           float* __restrict__ roww) {
    __shared__ int lbase[NE];
    __shared__ int lfill[NE];
    const int t = threadIdx.x;
    if (t == 0) {
        int b = 0;
        for (int e = 0; e < NE; e++) { lbase[e] = b; basep[e] = b; b += counts[e]; lfill[e] = 0; }
    }
    __syncthreads();
    for (int n = t; n < NTOK; n += blockDim.x) {
#pragma unroll
        for (int k = 0; k < 2; k++) {
            int e = sel[n * 2 + k];
            int p = atomicAdd(&lfill[e], 1);
            int g = lbase[e] + p;
            rowmap[g] = n; rowk[g] = k; roww[g] = selw[n * 2 + k];
        }
    }
}

// ---------------- x -> bf16 ----------------
__global__ void k_cvt(const float* __restrict__ x, unsigned short* __restrict__ xb) {
    size_t i = ((size_t)blockIdx.x * blockDim.x + threadIdx.x) * 8;
    float4 a = *(const float4*)(x + i);
    float4 b = *(const float4*)(x + i + 4);
    unsigned short p[8] __attribute__((aligned(16))) =
        { f2bf(a.x), f2bf(a.y), f2bf(a.z), f2bf(a.w),
          f2bf(b.x), f2bf(b.y), f2bf(b.z), f2bf(b.w) };
    *(uint4*)(xb + i) = *(uint4*)p;
}

// ---------------- weight transpose+convert -> tile-contiguous layout (r18) ----------------
// Per expert, 64x64 tiles of 4096 shorts:
//   w1t/w3t: tile_id = ftile*16 + ktile ; w2t: tile_id = ntile*56 + ktile.
// Within a tile: [n64][k64] row-major. Phase-B writes fully sequential.
__global__ void k_wt3(const float* __restrict__ w1, const float* __restrict__ w3,
                      const float* __restrict__ w2,
                      unsigned short* __restrict__ w1t, unsigned short* __restrict__ w3t,
                      unsigned short* __restrict__ w2t) {
    __shared__ unsigned int P[64 * 32];   // 8 KB pair layout: [n][32 k-pairs]
    const int z = blockIdx.z;
    int N, tx, ty;
    const float* src;
    unsigned short* dst;
    if (z < 16) {
        N = FD;
        const int e = z & 7;
        tx = blockIdx.x % (FD / 64); ty = blockIdx.x / (FD / 64);   // ftile, ktile
        src = (z < 8 ? w1 : w3) + (size_t)e * HD * FD;
        dst = (z < 8 ? w1t : w3t) + (size_t)e * HD * FD + ((size_t)tx * 16 + ty) * TSZ;
    } else {
        N = HD;
        const int e = z - 16;
        tx = blockIdx.x % (HD / 64); ty = blockIdx.x / (HD / 64);   // ntile, ktile
        src = w2 + (size_t)e * FD * HD;
        dst = w2t + (size_t)e * HD * FD + ((size_t)tx * 56 + ty) * TSZ;
    }
    src += (size_t)(ty * 64) * N + tx * 64;

    const int t = threadIdx.x;
    {
        const int rp = t >> 3;            // k-pair index 0..31
        const int c8 = t & 7;             // 8-col group
        const float* s0 = src + (size_t)(2 * rp) * N + c8 * 8;
        const float* s1 = s0 + N;
        float4 a0 = *(const float4*)(s0);
        float4 a1 = *(const float4*)(s0 + 4);
        float4 b0 = *(const float4*)(s1);
        float4 b1 = *(const float4*)(s1 + 4);
        float ev[8] = { a0.x, a0.y, a0.z, a0.w, a1.x, a1.y, a1.z, a1.w };
        float od[8] = { b0.x, b0.y, b0.z, b0.w, b1.x, b1.y, b1.z, b1.w };
#pragma unroll
        for (int j = 0; j < 8; j++) {
            const int n = c8 * 8 + j;
            unsigned int v = (unsigned int)f2bf(ev[j]) | ((unsigned int)f2bf(od[j]) << 16);
            P[n * 32 + (rp ^ ((n >> 3) << 2))] = v;
        }
    }
    __syncthreads();
    {
        const int n0 = t >> 3;            // 0..31
        const int q  = t & 7;             // k-octet 0..7
#pragma unroll
        for (int p = 0; p < 2; p++) {
            const int n = n0 + 32 * p;
            uint4 v = *(const uint4*)&P[n * 32 + 4 * (q ^ (n >> 3))];
            *(uint4*)&dst[n * 64 + q * 8] = v;   // sequential: thread t -> offset t*16B
        }
    }
}

// ---------------- GEMM1: 256 thr, 4 waves 2x2, wave tile 64x32 (r18) ----------------
__global__ __launch_bounds__(256, 2) void k_gemm1(
    const unsigned short* __restrict__ xb,
    const unsigned short* __restrict__ w1t, const unsigned short* __restrict__ w3t,
    const int* __restrict__ counts, const int* __restrict__ basep,
    const int* __restrict__ rowmap, unsigned short* __restrict__ act)
{
    const int e = blockIdx.z;
    const int nrows = counts[e];
    const int m0 = blockIdx.y * BM;
    if (m0 >= nrows) return;
    const int f0 = blockIdx.x * BN1;
    const int gbase = basep[e];

    __shared__ __align__(16) unsigned short At[2][BM][BK];
    __shared__ __align__(16) unsigned short B1[2][BN1][BK];
    __shared__ __align__(16) unsigned short B3[2][BN1][BK];

    const int t = threadIdx.x;
    const int lane = t & 63;
    const int w = t >> 6;                 // 0..3
    const int wrm = w >> 1, wnn = w & 1;  // 2x2 wave grid; wave tile 64 x 32
    const int lr = lane >> 3;
    const int so = ((lane & 7) ^ lr) * 8; // verified swizzle: chunk ^ (row&7)

    const unsigned short* asrc[4];
#pragma unroll
    for (int c = 0; c < 4; c++) {
        const int row = (w * 4 + c) * 8 + lr;
        const int tok = rowmap[gbase + min(m0 + row, nrows - 1)];
        asrc[c] = xb + (size_t)tok * HD + so;
    }
    // B: tile-contiguous layout; ftile = blockIdx.x (BN1==64). Per k-step the
    // whole staged tile is one contiguous 8KB block at + it*TSZ.
    const unsigned short* b1src[2];
    const unsigned short* b3src[2];
#pragma unroll
    for (int c = 0; c < 2; c++) {
        const int row = (w * 2 + c) * 8 + lr;
        const size_t tb = (size_t)e * HD * FD + ((size_t)blockIdx.x * 16) * TSZ + row * 64 + so;
        b1src[c] = w1t + tb;
        b3src[c] = w3t + tb;
    }

    f32x4 acc1[4][2], acc3[4][2];
#pragma unroll
    for (int i = 0; i < 4; i++)
#pragma unroll
        for (int j = 0; j < 2; j++) { acc1[i][j] = (f32x4)(0.f); acc3[i][j] = (f32x4)(0.f); }

    const int l15 = lane & 15;
    const int lhi = lane >> 4;
    const int rs = (l15 & 7) * 8;

    // prologue: stage k-tile 0 into buf 0 (8 loads/thread in flight)
#pragma unroll
    for (int c = 0; c < 4; c++) gl16(asrc[c], &At[0][(w * 4 + c) * 8][0]);
#pragma unroll
    for (int c = 0; c < 2; c++) {
        gl16(b1src[c], &B1[0][(w * 2 + c) * 8][0]);
        gl16(b3src[c], &B3[0][(w * 2 + c) * 8][0]);
    }

    for (int it = 0; it < NIT1; ++it) {
        const int cur = it & 1;
        if (it + 1 < NIT1) {
            const int kn = (it + 1) * BK;              // A offset (row-major xb)
            const size_t bt = (size_t)(it + 1) * TSZ;  // B offset (tile-contiguous)
#pragma unroll
            for (int c = 0; c < 4; c++) gl16(asrc[c] + kn, &At[cur ^ 1][(w * 4 + c) * 8][0]);
#pragma unroll
            for (int c = 0; c < 2; c++) {
                gl16(b1src[c] + bt, &B1[cur ^ 1][(w * 2 + c) * 8][0]);
                gl16(b3src[c] + bt, &B3[cur ^ 1][(w * 2 + c) * 8][0]);
            }
            asm volatile("s_waitcnt vmcnt(8)" ::: "memory");   // wait current tile only
        } else {
            asm volatile("s_waitcnt vmcnt(0)" ::: "memory");
        }
        __builtin_amdgcn_s_barrier();
#pragma unroll
        for (int kk = 0; kk < 2; kk++) {
            const int kc = (kk * 32 + lhi * 8) ^ rs;
            short8 af[4], b1f[2], b3f[2];
#pragma unroll
            for (int i = 0; i < 4; i++)
                af[i] = *(const short8*)&At[cur][wrm * 64 + i * 16 + l15][kc];
#pragma unroll
            for (int j = 0; j < 2; j++) {
                b1f[j] = *(const short8*)&B1[cur][wnn * 32 + j * 16 + l15][kc];
                b3f[j] = *(const short8*)&B3[cur][wnn * 32 + j * 16 + l15][kc];
            }
#pragma unroll
            for (int i = 0; i < 4; i++)
#pragma unroll
                for (int j = 0; j < 2; j++) {
                    acc1[i][j] = __builtin_amdgcn_mfma_f32_16x16x32_bf16(af[i], b1f[j], acc1[i][j], 0, 0, 0);
                    acc3[i][j] = __builtin_amdgcn_mfma_f32_16x16x32_bf16(af[i], b3f[j], acc3[i][j], 0, 0, 0);
                }
        }
        __builtin_amdgcn_s_barrier();
    }

    // epilogue: SwiGLU, bf16 act
    const int rbase = wrm * 64 + lhi * 4;
    const int cbase = f0 + wnn * 32 + l15;
#pragma unroll
    for (int i = 0; i < 4; i++) {
#pragma unroll
        for (int r = 0; r < 4; r++) {
            const int ml = rbase + i * 16 + r;
            if (m0 + ml < nrows) {
                const size_t rowoff = (size_t)(gbase + m0 + ml) * FD;
#pragma unroll
                for (int j = 0; j < 2; j++) {
                    float y1 = acc1[i][j][r];
                    float y3 = acc3[i][j][r];
                    float sv = (y1 / (1.f + __expf(-y1))) * y3;
                    act[rowoff + cbase + j * 16] = f2bf(sv);
                }
            }
        }
    }
}

// ---------------- GEMM2: BM2=64 x BN=128, wave tile 32x64, K-split x2 (r18) ----------------
// Epilogue atomically accumulates into out.
__global__ __launch_bounds__(256, 4) void k_gemm2(
    const unsigned short* __restrict__ act,
    const unsigned short* __restrict__ w2t,
    const int* __restrict__ counts, const int* __restrict__ basep,
    const int* __restrict__ rowmap, const int* __restrict__ rowk,
    const float* __restrict__ roww, float* __restrict__ out)
{
    const int z = blockIdx.z;
    const int e = z >> 1, ks = z & 1;
    const int nrows = counts[e];
    const int m0 = blockIdx.y * BM2;
    if (m0 >= nrows) return;
    const int h0 = blockIdx.x * BN;
    const int gbase = basep[e];
    const int kbase = ks * KLEN2;

    __shared__ __align__(16) unsigned short At[2][BM2][BK];
    __shared__ __align__(16) unsigned short Bt[2][BN][BK];

    const int t = threadIdx.x;
    const int lane = t & 63;
    const int w = t >> 6;                 // 0..3
    const int wr2 = w >> 1, wn2 = w & 1;  // 2x2; wave tile 32 x 64
    const int lr = lane >> 3;
    const int so = ((lane & 7) ^ lr) * 8;

    const unsigned short* asrc[2];
#pragma unroll
    for (int c = 0; c < 2; c++) {
        const int row = (w * 2 + c) * 8 + lr;
        asrc[c] = act + ((size_t)gbase + min(m0 + row, nrows - 1)) * FD + so + kbase;
    }
    // B: tile-contiguous w2t; ntile = h0/64 + (row>>6); k-split offset ks*28 tiles.
    const unsigned short* bsrc[4];
#pragma unroll
    for (int c = 0; c < 4; c++) {
        const int row = (w * 4 + c) * 8 + lr;
        const int ntile = (h0 >> 6) + (row >> 6);
        bsrc[c] = w2t + (size_t)e * HD * FD + ((size_t)ntile * 56 + ks * 28) * TSZ
                + (row & 63) * 64 + so;
    }

    f32x4 acc[2][4];
#pragma unroll
    for (int i = 0; i < 2; i++)
#pragma unroll
        for (int j = 0; j < 4; j++) acc[i][j] = (f32x4)(0.f);

    const int l15 = lane & 15;
    const int lhi = lane >> 4;
    const int rs = (l15 & 7) * 8;

    // prologue: stage tile 0 into buf 0 (6 loads/thread)
#pragma unroll
    for (int c = 0; c < 2; c++) gl16(asrc[c], &At[0][(w * 2 + c) * 8][0]);
#pragma unroll
    for (int c = 0; c < 4; c++) gl16(bsrc[c], &Bt[0][(w * 4 + c) * 8][0]);

    for (int it = 0; it < NIT2; ++it) {
        const int cur = it & 1;
        if (it + 1 < NIT2) {
            const int kn = (it + 1) * BK;
            const size_t bt = (size_t)(it + 1) * TSZ;
#pragma unroll
            for (int c = 0; c < 2; c++) gl16(asrc[c] + kn, &At[cur ^ 1][(w * 2 + c) * 8][0]);
#pragma unroll
            for (int c = 0; c < 4; c++) gl16(bsrc[c] + bt, &Bt[cur ^ 1][(w * 4 + c) * 8][0]);
            asm volatile("s_waitcnt vmcnt(6)" ::: "memory");
        } else {
            asm volatile("s_waitcnt vmcnt(0)" ::: "memory");
        }
        __builtin_amdgcn_s_barrier();
#pragma unroll
        for (int kk = 0; kk < 2; kk++) {
            const int kc = (kk * 32 + lhi * 8) ^ rs;
            short8 af[2], bf[4];
#pragma unroll
            for (int i = 0; i < 2; i++)
                af[i] = *(const short8*)&At[cur][wr2 * 32 + i * 16 + l15][kc];
#pragma unroll
            for (int j = 0; j < 4; j++)
                bf[j] = *(const short8*)&Bt[cur][wn2 * 64 + j * 16 + l15][kc];
#pragma unroll
            for (int i = 0; i < 2; i++)
#pragma unroll
                for (int j = 0; j < 4; j++)
                    acc[i][j] = __builtin_amdgcn_mfma_f32_16x16x32_bf16(af[i], bf[j], acc[i][j], 0, 0, 0);
        }
        __builtin_amdgcn_s_barrier();
    }

    const int rbase = wr2 * 32 + lhi * 4;
    const int cbase = h0 + wn2 * 64 + l15;
#pragma unroll
    for (int i = 0; i < 2; i++) {
#pragma unroll
        for (int r = 0; r < 4; r++) {
            const int ml = rbase + i * 16 + r;
            if (m0 + ml < nrows) {
                const int grow = gbase + m0 + ml;
                const int tok = rowmap[grow];
                const float wv = roww[grow];
                float* op = out + (size_t)tok * HD + cbase;
#pragma unroll
                for (int j = 0; j < 4; j++)
                    atomicAdd(&op[j * 16], acc[i][j][r] * wv);
            }
        }
    }
}

extern "C" void kernel_launch(void* const* d_in, const int* in_sizes, int n_in,
                              void* d_out, int out_size, void* d_ws, size_t ws_size,
                              hipStream_t stream) {
    const float* x  = (const float*)d_in[0];
    const float* gw = (const float*)d_in[1];
    const float* w1 = (const float*)d_in[2];
    const float* w3 = (const float*)d_in[3];
    const float* w2 = (const float*)d_in[4];
    float* out = (float*)d_out;

    char* ws = (char*)d_ws;
    size_t off = 0;
    auto alloc = [&](size_t b) { char* p = ws + off; off += (b + 255) & ~(size_t)255; return p; };
    int*   sel    = (int*)  alloc((size_t)NTOK * 2 * 4);
    float* selw   = (float*)alloc((size_t)NTOK * 2 * 4);
    int*   counts = (int*)  alloc(NE * 4);
    int*   basep  = (int*)  alloc(NE * 4);
    int*   rowmap = (int*)  alloc((size_t)NTOK * 2 * 4);
    int*   rowk   = (int*)  alloc((size_t)NTOK * 2 * 4);
    float* roww   = (float*)alloc((size_t)NTOK * 2 * 4);
    unsigned short* xb  = (unsigned short*)alloc((size_t)NTOK * HD * 2);
    unsigned short* act = (unsigned short*)alloc((size_t)NTOK * 2 * FD * 2);
    unsigned short* w1t = (unsigned short*)alloc((size_t)NE * HD * FD * 2);
    unsigned short* w3t = (unsigned short*)alloc((size_t)NE * HD * FD * 2);
    unsigned short* w2t = (unsigned short*)alloc((size_t)NE * HD * FD * 2);

    hipMemsetAsync(counts, 0, NE * 4, stream);
    hipMemsetAsync(out, 0, (size_t)out_size * 4, stream);   // gemm2 accumulates atomically
    k_wt3<<<dim3(896, 1, 24), 256, 0, stream>>>(w1, w3, w2, w1t, w3t, w2t);
    k_cvt<<<(NTOK * HD) / (256 * 8), 256, 0, stream>>>(x, xb);
    k_router<<<NTOK / 4, 256, 0, stream>>>(x, gw, sel, selw, counts);
    k_scanfill<<<1, 256, 0, stream>>>(counts, sel, selw, basep, rowmap, rowk, roww);
    k_gemm1<<<dim3(FD / BN1, NTOK / BM, NE), 256, 0, stream>>>(xb, w1t, w3t, counts, basep, rowmap, act);
    k_gemm2<<<dim3(HD / BN, NTOK / BM2, NE * KS2), 256, 0, stream>>>(act, w2t, counts, basep, rowmap, rowk, roww, out);
}

// Round 22
// 313.557 us; speedup vs baseline: 1.1330x; 1.0147x over previous
//
#include <hip/hip_runtime.h>
#include <hip/hip_bf16.h>

#define NTOK 2048   // B*S
#define HD   1024
#define FD   3584
#define NE   8

#define BM 128              // gemm1 m-tile
#define BN1 64              // gemm1 f-tile
#define BM2 64              // gemm2 m-tile
#define BN 128              // gemm2 h-tile
#define BK 64               // 128B LDS rows (verified conflict-free layout)
#define NIT1 (HD / BK)      // 16
#define KS2 2               // gemm2 K-split
#define KLEN2 (FD / KS2)    // 1792
#define NIT2 (KLEN2 / BK)   // 28
#define TSZ 4096            // shorts per 64x64 weight tile (8KB)

typedef __attribute__((ext_vector_type(8))) short short8;
typedef __attribute__((ext_vector_type(4))) float f32x4;

__device__ __forceinline__ unsigned short f2bf(float f) {
    __hip_bfloat16 h = __float2bfloat16(f);
    union { __hip_bfloat16 h; unsigned short u; } c; c.h = h;
    return c.u;
}

// global_load_lds width=16: per-lane 16B global src -> wave-uniform LDS base + lane*16
typedef __attribute__((address_space(1))) const unsigned int g_cu32;
typedef __attribute__((address_space(3))) unsigned int l_u32;
__device__ __forceinline__ void gl16(const void* g, void* l) {
    __builtin_amdgcn_global_load_lds((g_cu32*)g, (l_u32*)(unsigned int)(size_t)l, 16, 0, 0);
}

// ---------------- router + x->bf16 (fused): one read of x serves both ----------------
// Block = 4 waves = 4 tokens. Lane owns 16 contiguous floats (4 float4) of its
// token's row: converts+stores bf16 to xb AND accumulates the 8 gate logits.
__global__ void k_router(const float* __restrict__ x, const float* __restrict__ gw,
                         unsigned short* __restrict__ xb,
                         int* __restrict__ sel, float* __restrict__ selw,
                         int* __restrict__ counts) {
    int token = blockIdx.x * 4 + (threadIdx.x >> 6);
    int lane  = threadIdx.x & 63;
    if (token >= NTOK) return;
    const float* xr = x + (size_t)token * HD;
    const int h0 = lane * 16;

    float4 v[4];
#pragma unroll
    for (int i = 0; i < 4; i++) v[i] = *(const float4*)(xr + h0 + i * 4);

    // bf16 convert + store (16 values = 2 uint4)
    {
        unsigned short p[16] __attribute__((aligned(16)));
#pragma unroll
        for (int i = 0; i < 4; i++) {
            p[i * 4 + 0] = f2bf(v[i].x); p[i * 4 + 1] = f2bf(v[i].y);
            p[i * 4 + 2] = f2bf(v[i].z); p[i * 4 + 3] = f2bf(v[i].w);
        }
        unsigned short* xo = xb + (size_t)token * HD + h0;
        *(uint4*)(xo)     = *(uint4*)&p[0];
        *(uint4*)(xo + 8) = *(uint4*)&p[8];
    }

    // gate logits from the same registers
    float acc[NE];
#pragma unroll
    for (int e = 0; e < NE; e++) acc[e] = 0.f;
#pragma unroll
    for (int i = 0; i < 4; i++) {
        const float* vf = (const float*)&v[i];
#pragma unroll
        for (int j = 0; j < 4; j++) {
            const float xv = vf[j];
            const float4* g = (const float4*)(gw + (size_t)(h0 + i * 4 + j) * NE);
            float4 g0 = g[0], g1 = g[1];
            acc[0] += xv * g0.x; acc[1] += xv * g0.y; acc[2] += xv * g0.z; acc[3] += xv * g0.w;
            acc[4] += xv * g1.x; acc[5] += xv * g1.y; acc[6] += xv * g1.z; acc[7] += xv * g1.w;
        }
    }
#pragma unroll
    for (int e = 0; e < NE; e++) {
#pragma unroll
        for (int off = 32; off >= 1; off >>= 1) acc[e] += __shfl_xor(acc[e], off, 64);
    }
    if (lane == 0) {
        float m = acc[0];
#pragma unroll
        for (int e = 1; e < NE; e++) m = fmaxf(m, acc[e]);
        float z[NE];
#pragma unroll
        for (int e = 0; e < NE; e++) z[e] = expf(acc[e] - m);
        int e0 = 0; float z0 = z[0];
#pragma unroll
        for (int e = 1; e < NE; e++) if (z[e] > z0) { z0 = z[e]; e0 = e; }
        int e1 = -1; float z1 = -1.f;
#pragma unroll
        for (int e = 0; e < NE; e++) if (e != e0 && z[e] > z1) { z1 = z[e]; e1 = e; }
        float s = z0 + z1;
        sel[token * 2 + 0] = e0; sel[token * 2 + 1] = e1;
        selw[token * 2 + 0] = z0 / s; selw[token * 2 + 1] = z1 / s;
        atomicAdd(&counts[e0], 1);
        atomicAdd(&counts[e1], 1);
    }
}

// ---------------- fused scan+fill: 1 block; scan in LDS, grid-stride fill ----------------
__global__ void k_scanfill(const int* __restrict__ counts, const int* __restrict__ sel,
                           const float* __restrict__ selw, int* __restrict__ basep,
                           int* __restrict__ rowmap, int* __restrict__ rowk,
                           float* __restrict__ roww) {
    __shared__ int lbase[NE];
    __shared__ int lfill[NE];
    const int t = threadIdx.x;
    if (t == 0) {
        int b = 0;
        for (int e = 0; e < NE; e++) { lbase[e] = b; basep[e] = b; b += counts[e]; lfill[e] = 0; }
    }
    __syncthreads();
    for (int n = t; n < NTOK; n += blockDim.x) {
#pragma unroll
        for (int k = 0; k < 2; k++) {
            int e = sel[n * 2 + k];
            int p = atomicAdd(&lfill[e], 1);
            int g = lbase[e] + p;
            rowmap[g] = n; rowk[g] = k; roww[g] = selw[n * 2 + k];
        }
    }
}

// ---------------- weight transpose+convert -> tile-contiguous layout (r18) ----------------
// Per expert, 64x64 tiles of 4096 shorts:
//   w1t/w3t: tile_id = ftile*16 + ktile ; w2t: tile_id = ntile*56 + ktile.
// Within a tile: [n64][k64] row-major. Phase-B writes fully sequential.
__global__ void k_wt3(const float* __restrict__ w1, const float* __restrict__ w3,
                      const float* __restrict__ w2,
                      unsigned short* __restrict__ w1t, unsigned short* __restrict__ w3t,
                      unsigned short* __restrict__ w2t) {
    __shared__ unsigned int P[64 * 32];   // 8 KB pair layout: [n][32 k-pairs]
    const int z = blockIdx.z;
    int N, tx, ty;
    const float* src;
    unsigned short* dst;
    if (z < 16) {
        N = FD;
        const int e = z & 7;
        tx = blockIdx.x % (FD / 64); ty = blockIdx.x / (FD / 64);   // ftile, ktile
        src = (z < 8 ? w1 : w3) + (size_t)e * HD * FD;
        dst = (z < 8 ? w1t : w3t) + (size_t)e * HD * FD + ((size_t)tx * 16 + ty) * TSZ;
    } else {
        N = HD;
        const int e = z - 16;
        tx = blockIdx.x % (HD / 64); ty = blockIdx.x / (HD / 64);   // ntile, ktile
        src = w2 + (size_t)e * FD * HD;
        dst = w2t + (size_t)e * HD * FD + ((size_t)tx * 56 + ty) * TSZ;
    }
    src += (size_t)(ty * 64) * N + tx * 64;

    const int t = threadIdx.x;
    {
        const int rp = t >> 3;            // k-pair index 0..31
        const int c8 = t & 7;             // 8-col group
        const float* s0 = src + (size_t)(2 * rp) * N + c8 * 8;
        const float* s1 = s0 + N;
        float4 a0 = *(const float4*)(s0);
        float4 a1 = *(const float4*)(s0 + 4);
        float4 b0 = *(const float4*)(s1);
        float4 b1 = *(const float4*)(s1 + 4);
        float ev[8] = { a0.x, a0.y, a0.z, a0.w, a1.x, a1.y, a1.z, a1.w };
        float od[8] = { b0.x, b0.y, b0.z, b0.w, b1.x, b1.y, b1.z, b1.w };
#pragma unroll
        for (int j = 0; j < 8; j++) {
            const int n = c8 * 8 + j;
            unsigned int v = (unsigned int)f2bf(ev[j]) | ((unsigned int)f2bf(od[j]) << 16);
            P[n * 32 + (rp ^ ((n >> 3) << 2))] = v;
        }
    }
    __syncthreads();
    {
        const int n0 = t >> 3;            // 0..31
        const int q  = t & 7;             // k-octet 0..7
#pragma unroll
        for (int p = 0; p < 2; p++) {
            const int n = n0 + 32 * p;
            uint4 v = *(const uint4*)&P[n * 32 + 4 * (q ^ (n >> 3))];
            *(uint4*)&dst[n * 64 + q * 8] = v;   // sequential: thread t -> offset t*16B
        }
    }
}

// ---------------- GEMM1: 256 thr, 4 waves 2x2, wave tile 64x32 (r18) ----------------
__global__ __launch_bounds__(256, 2) void k_gemm1(
    const unsigned short* __restrict__ xb,
    const unsigned short* __restrict__ w1t, const unsigned short* __restrict__ w3t,
    const int* __restrict__ counts, const int* __restrict__ basep,
    const int* __restrict__ rowmap, unsigned short* __restrict__ act)
{
    const int e = blockIdx.z;
    const int nrows = counts[e];
    const int m0 = blockIdx.y * BM;
    if (m0 >= nrows) return;
    const int f0 = blockIdx.x * BN1;
    const int gbase = basep[e];

    __shared__ __align__(16) unsigned short At[2][BM][BK];
    __shared__ __align__(16) unsigned short B1[2][BN1][BK];
    __shared__ __align__(16) unsigned short B3[2][BN1][BK];

    const int t = threadIdx.x;
    const int lane = t & 63;
    const int w = t >> 6;                 // 0..3
    const int wrm = w >> 1, wnn = w & 1;  // 2x2 wave grid; wave tile 64 x 32
    const int lr = lane >> 3;
    const int so = ((lane & 7) ^ lr) * 8; // verified swizzle: chunk ^ (row&7)

    const unsigned short* asrc[4];
#pragma unroll
    for (int c = 0; c < 4; c++) {
        const int row = (w * 4 + c) * 8 + lr;
        const int tok = rowmap[gbase + min(m0 + row, nrows - 1)];
        asrc[c] = xb + (size_t)tok * HD + so;
    }
    // B: tile-contiguous layout; ftile = blockIdx.x (BN1==64). Per k-step the
    // whole staged tile is one contiguous 8KB block at + it*TSZ.
    const unsigned short* b1src[2];
    const unsigned short* b3src[2];
#pragma unroll
    for (int c = 0; c < 2; c++) {
        const int row = (w * 2 + c) * 8 + lr;
        const size_t tb = (size_t)e * HD * FD + ((size_t)blockIdx.x * 16) * TSZ + row * 64 + so;
        b1src[c] = w1t + tb;
        b3src[c] = w3t + tb;
    }

    f32x4 acc1[4][2], acc3[4][2];
#pragma unroll
    for (int i = 0; i < 4; i++)
#pragma unroll
        for (int j = 0; j < 2; j++) { acc1[i][j] = (f32x4)(0.f); acc3[i][j] = (f32x4)(0.f); }

    const int l15 = lane & 15;
    const int lhi = lane >> 4;
    const int rs = (l15 & 7) * 8;

    // prologue: stage k-tile 0 into buf 0 (8 loads/thread in flight)
#pragma unroll
    for (int c = 0; c < 4; c++) gl16(asrc[c], &At[0][(w * 4 + c) * 8][0]);
#pragma unroll
    for (int c = 0; c < 2; c++) {
        gl16(b1src[c], &B1[0][(w * 2 + c) * 8][0]);
        gl16(b3src[c], &B3[0][(w * 2 + c) * 8][0]);
    }

    for (int it = 0; it < NIT1; ++it) {
        const int cur = it & 1;
        if (it + 1 < NIT1) {
            const int kn = (it + 1) * BK;              // A offset (row-major xb)
            const size_t bt = (size_t)(it + 1) * TSZ;  // B offset (tile-contiguous)
#pragma unroll
            for (int c = 0; c < 4; c++) gl16(asrc[c] + kn, &At[cur ^ 1][(w * 4 + c) * 8][0]);
#pragma unroll
            for (int c = 0; c < 2; c++) {
                gl16(b1src[c] + bt, &B1[cur ^ 1][(w * 2 + c) * 8][0]);
                gl16(b3src[c] + bt, &B3[cur ^ 1][(w * 2 + c) * 8][0]);
            }
            asm volatile("s_waitcnt vmcnt(8)" ::: "memory");   // wait current tile only
        } else {
            asm volatile("s_waitcnt vmcnt(0)" ::: "memory");
        }
        __builtin_amdgcn_s_barrier();
#pragma unroll
        for (int kk = 0; kk < 2; kk++) {
            const int kc = (kk * 32 + lhi * 8) ^ rs;
            short8 af[4], b1f[2], b3f[2];
#pragma unroll
            for (int i = 0; i < 4; i++)
                af[i] = *(const short8*)&At[cur][wrm * 64 + i * 16 + l15][kc];
#pragma unroll
            for (int j = 0; j < 2; j++) {
                b1f[j] = *(const short8*)&B1[cur][wnn * 32 + j * 16 + l15][kc];
                b3f[j] = *(const short8*)&B3[cur][wnn * 32 + j * 16 + l15][kc];
            }
#pragma unroll
            for (int i = 0; i < 4; i++)
#pragma unroll
                for (int j = 0; j < 2; j++) {
                    acc1[i][j] = __builtin_amdgcn_mfma_f32_16x16x32_bf16(af[i], b1f[j], acc1[i][j], 0, 0, 0);
                    acc3[i][j] = __builtin_amdgcn_mfma_f32_16x16x32_bf16(af[i], b3f[j], acc3[i][j], 0, 0, 0);
                }
        }
        __builtin_amdgcn_s_barrier();
    }

    // epilogue: SwiGLU, bf16 act
    const int rbase = wrm * 64 + lhi * 4;
    const int cbase = f0 + wnn * 32 + l15;
#pragma unroll
    for (int i = 0; i < 4; i++) {
#pragma unroll
        for (int r = 0; r < 4; r++) {
            const int ml = rbase + i * 16 + r;
            if (m0 + ml < nrows) {
                const size_t rowoff = (size_t)(gbase + m0 + ml) * FD;
#pragma unroll
                for (int j = 0; j < 2; j++) {
                    float y1 = acc1[i][j][r];
                    float y3 = acc3[i][j][r];
                    float sv = (y1 / (1.f + __expf(-y1))) * y3;
                    act[rowoff + cbase + j * 16] = f2bf(sv);
                }
            }
        }
    }
}

// ---------------- GEMM2: BM2=64 x BN=128, wave tile 32x64, K-split x2 (r18) ----------------
// Epilogue atomically accumulates into out.
__global__ __launch_bounds__(256, 4) void k_gemm2(
    const unsigned short* __restrict__ act,
    const unsigned short* __restrict__ w2t,
    const int* __restrict__ counts, const int* __restrict__ basep,
    const int* __restrict__ rowmap, const int* __restrict__ rowk,
    const float* __restrict__ roww, float* __restrict__ out)
{
    const int z = blockIdx.z;
    const int e = z >> 1, ks = z & 1;
    const int nrows = counts[e];
    const int m0 = blockIdx.y * BM2;
    if (m0 >= nrows) return;
    const int h0 = blockIdx.x * BN;
    const int gbase = basep[e];
    const int kbase = ks * KLEN2;

    __shared__ __align__(16) unsigned short At[2][BM2][BK];
    __shared__ __align__(16) unsigned short Bt[2][BN][BK];

    const int t = threadIdx.x;
    const int lane = t & 63;
    const int w = t >> 6;                 // 0..3
    const int wr2 = w >> 1, wn2 = w & 1;  // 2x2; wave tile 32 x 64
    const int lr = lane >> 3;
    const int so = ((lane & 7) ^ lr) * 8;

    const unsigned short* asrc[2];
#pragma unroll
    for (int c = 0; c < 2; c++) {
        const int row = (w * 2 + c) * 8 + lr;
        asrc[c] = act + ((size_t)gbase + min(m0 + row, nrows - 1)) * FD + so + kbase;
    }
    // B: tile-contiguous w2t; ntile = h0/64 + (row>>6); k-split offset ks*28 tiles.
    const unsigned short* bsrc[4];
#pragma unroll
    for (int c = 0; c < 4; c++) {
        const int row = (w * 4 + c) * 8 + lr;
        const int ntile = (h0 >> 6) + (row >> 6);
        bsrc[c] = w2t + (size_t)e * HD * FD + ((size_t)ntile * 56 + ks * 28) * TSZ
                + (row & 63) * 64 + so;
    }

    f32x4 acc[2][4];
#pragma unroll
    for (int i = 0; i < 2; i++)
#pragma unroll
        for (int j = 0; j < 4; j++) acc[i][j] = (f32x4)(0.f);

    const int l15 = lane & 15;
    const int lhi = lane >> 4;
    const int rs = (l15 & 7) * 8;

    // prologue: stage tile 0 into buf 0 (6 loads/thread)
#pragma unroll
    for (int c = 0; c < 2; c++) gl16(asrc[c], &At[0][(w * 2 + c) * 8][0]);
#pragma unroll
    for (int c = 0; c < 4; c++) gl16(bsrc[c], &Bt[0][(w * 4 + c) * 8][0]);

    for (int it = 0; it < NIT2; ++it) {
        const int cur = it & 1;
        if (it + 1 < NIT2) {
            const int kn = (it + 1) * BK;
            const size_t bt = (size_t)(it + 1) * TSZ;
#pragma unroll
            for (int c = 0; c < 2; c++) gl16(asrc[c] + kn, &At[cur ^ 1][(w * 2 + c) * 8][0]);
#pragma unroll
            for (int c = 0; c < 4; c++) gl16(bsrc[c] + bt, &Bt[cur ^ 1][(w * 4 + c) * 8][0]);
            asm volatile("s_waitcnt vmcnt(6)" ::: "memory");
        } else {
            asm volatile("s_waitcnt vmcnt(0)" ::: "memory");
        }
        __builtin_amdgcn_s_barrier();
#pragma unroll
        for (int kk = 0; kk < 2; kk++) {
            const int kc = (kk * 32 + lhi * 8) ^ rs;
            short8 af[2], bf[4];
#pragma unroll
            for (int i = 0; i < 2; i++)
                af[i] = *(const short8*)&At[cur][wr2 * 32 + i * 16 + l15][kc];
#pragma unroll
            for (int j = 0; j < 4; j++)
                bf[j] = *(const short8*)&Bt[cur][wn2 * 64 + j * 16 + l15][kc];
#pragma unroll
            for (int i = 0; i < 2; i++)
#pragma unroll
                for (int j = 0; j < 4; j++)
                    acc[i][j] = __builtin_amdgcn_mfma_f32_16x16x32_bf16(af[i], bf[j], acc[i][j], 0, 0, 0);
        }
        __builtin_amdgcn_s_barrier();
    }

    const int rbase = wr2 * 32 + lhi * 4;
    const int cbase = h0 + wn2 * 64 + l15;
#pragma unroll
    for (int i = 0; i < 2; i++) {
#pragma unroll
        for (int r = 0; r < 4; r++) {
            const int ml = rbase + i * 16 + r;
            if (m0 + ml < nrows) {
                const int grow = gbase + m0 + ml;
                const int tok = rowmap[grow];
                const float wv = roww[grow];
                float* op = out + (size_t)tok * HD + cbase;
#pragma unroll
                for (int j = 0; j < 4; j++)
                    atomicAdd(&op[j * 16], acc[i][j][r] * wv);
            }
        }
    }
}

extern "C" void kernel_launch(void* const* d_in, const int* in_sizes, int n_in,
                              void* d_out, int out_size, void* d_ws, size_t ws_size,
                              hipStream_t stream) {
    const float* x  = (const float*)d_in[0];
    const float* gw = (const float*)d_in[1];
    const float* w1 = (const float*)d_in[2];
    const float* w3 = (const float*)d_in[3];
    const float* w2 = (const float*)d_in[4];
    float* out = (float*)d_out;

    char* ws = (char*)d_ws;
    size_t off = 0;
    auto alloc = [&](size_t b) { char* p = ws + off; off += (b + 255) & ~(size_t)255; return p; };
    int*   sel    = (int*)  alloc((size_t)NTOK * 2 * 4);
    float* selw   = (float*)alloc((size_t)NTOK * 2 * 4);
    int*   counts = (int*)  alloc(NE * 4);
    int*   basep  = (int*)  alloc(NE * 4);
    int*   rowmap = (int*)  alloc((size_t)NTOK * 2 * 4);
    int*   rowk   = (int*)  alloc((size_t)NTOK * 2 * 4);
    float* roww   = (float*)alloc((size_t)NTOK * 2 * 4);
    unsigned short* xb  = (unsigned short*)alloc((size_t)NTOK * HD * 2);
    unsigned short* act = (unsigned short*)alloc((size_t)NTOK * 2 * FD * 2);
    unsigned short* w1t = (unsigned short*)alloc((size_t)NE * HD * FD * 2);
    unsigned short* w3t = (unsigned short*)alloc((size_t)NE * HD * FD * 2);
    unsigned short* w2t = (unsigned short*)alloc((size_t)NE * HD * FD * 2);

    hipMemsetAsync(counts, 0, NE * 4, stream);
    hipMemsetAsync(out, 0, (size_t)out_size * 4, stream);   // gemm2 accumulates atomically
    k_wt3<<<dim3(896, 1, 24), 256, 0, stream>>>(w1, w3, w2, w1t, w3t, w2t);
    k_router<<<NTOK / 4, 256, 0, stream>>>(x, gw, xb, sel, selw, counts);
    k_scanfill<<<1, 256, 0, stream>>>(counts, sel, selw, basep, rowmap, rowk, roww);
    k_gemm1<<<dim3(FD / BN1, NTOK / BM, NE), 256, 0, stream>>>(xb, w1t, w3t, counts, basep, rowmap, act);
    k_gemm2<<<dim3(HD / BN, NTOK / BM2, NE * KS2), 256, 0, stream>>>(act, w2t, counts, basep, rowmap, rowk, roww, out);
}

// Round 24
// 305.390 us; speedup vs baseline: 1.1633x; 1.0267x over previous
//
#include <hip/hip_runtime.h>
#include <hip/hip_bf16.h>

#define NTOK 2048   // B*S
#define HD   1024
#define FD   3584
#define NE   8

#define BM 128              // gemm1 m-tile
#define BN1 64              // gemm1 f-tile
#define BM2 64              // gemm2 m-tile
#define BN 128              // gemm2 h-tile
#define BK 64               // 128B LDS rows (verified conflict-free layout)
#define NIT1 (HD / BK)      // 16
#define KS2 2               // gemm2 K-split
#define KLEN2 (FD / KS2)    // 1792
#define NIT2 (KLEN2 / BK)   // 28
#define TSZ 4096            // shorts per 64x64 weight tile (8KB)

typedef __attribute__((ext_vector_type(8))) short short8;
typedef __attribute__((ext_vector_type(4))) float f32x4;
typedef __attribute__((ext_vector_type(4))) unsigned int u32x4;  // native vec for NT stores

__device__ __forceinline__ unsigned short f2bf(float f) {
    __hip_bfloat16 h = __float2bfloat16(f);
    union { __hip_bfloat16 h; unsigned short u; } c; c.h = h;
    return c.u;
}

// global_load_lds width=16: per-lane 16B global src -> wave-uniform LDS base + lane*16
typedef __attribute__((address_space(1))) const unsigned int g_cu32;
typedef __attribute__((address_space(3))) unsigned int l_u32;
__device__ __forceinline__ void gl16(const void* g, void* l) {
    __builtin_amdgcn_global_load_lds((g_cu32*)g, (l_u32*)(unsigned int)(size_t)l, 16, 0, 0);
}

// ---------------- router + x->bf16 (fused): one read of x serves both ----------------
__global__ void k_router(const float* __restrict__ x, const float* __restrict__ gw,
                         unsigned short* __restrict__ xb,
                         int* __restrict__ sel, float* __restrict__ selw,
                         int* __restrict__ counts) {
    int token = blockIdx.x * 4 + (threadIdx.x >> 6);
    int lane  = threadIdx.x & 63;
    if (token >= NTOK) return;
    const float* xr = x + (size_t)token * HD;
    const int h0 = lane * 16;

    float4 v[4];
#pragma unroll
    for (int i = 0; i < 4; i++) v[i] = *(const float4*)(xr + h0 + i * 4);

    {
        unsigned short p[16] __attribute__((aligned(16)));
#pragma unroll
        for (int i = 0; i < 4; i++) {
            p[i * 4 + 0] = f2bf(v[i].x); p[i * 4 + 1] = f2bf(v[i].y);
            p[i * 4 + 2] = f2bf(v[i].z); p[i * 4 + 3] = f2bf(v[i].w);
        }
        unsigned short* xo = xb + (size_t)token * HD + h0;
        *(uint4*)(xo)     = *(uint4*)&p[0];
        *(uint4*)(xo + 8) = *(uint4*)&p[8];
    }

    float acc[NE];
#pragma unroll
    for (int e = 0; e < NE; e++) acc[e] = 0.f;
#pragma unroll
    for (int i = 0; i < 4; i++) {
        const float* vf = (const float*)&v[i];
#pragma unroll
        for (int j = 0; j < 4; j++) {
            const float xv = vf[j];
            const float4* g = (const float4*)(gw + (size_t)(h0 + i * 4 + j) * NE);
            float4 g0 = g[0], g1 = g[1];
            acc[0] += xv * g0.x; acc[1] += xv * g0.y; acc[2] += xv * g0.z; acc[3] += xv * g0.w;
            acc[4] += xv * g1.x; acc[5] += xv * g1.y; acc[6] += xv * g1.z; acc[7] += xv * g1.w;
        }
    }
#pragma unroll
    for (int e = 0; e < NE; e++) {
#pragma unroll
        for (int off = 32; off >= 1; off >>= 1) acc[e] += __shfl_xor(acc[e], off, 64);
    }
    if (lane == 0) {
        float m = acc[0];
#pragma unroll
        for (int e = 1; e < NE; e++) m = fmaxf(m, acc[e]);
        float z[NE];
#pragma unroll
        for (int e = 0; e < NE; e++) z[e] = expf(acc[e] - m);
        int e0 = 0; float z0 = z[0];
#pragma unroll
        for (int e = 1; e < NE; e++) if (z[e] > z0) { z0 = z[e]; e0 = e; }
        int e1 = -1; float z1 = -1.f;
#pragma unroll
        for (int e = 0; e < NE; e++) if (e != e0 && z[e] > z1) { z1 = z[e]; e1 = e; }
        float s = z0 + z1;
        sel[token * 2 + 0] = e0; sel[token * 2 + 1] = e1;
        selw[token * 2 + 0] = z0 / s; selw[token * 2 + 1] = z1 / s;
        atomicAdd(&counts[e0], 1);
        atomicAdd(&counts[e1], 1);
    }
}

// ---------------- fused scan+fill: 1 block; scan in LDS, grid-stride fill ----------------
__global__ void k_scanfill(const int* __restrict__ counts, const int* __restrict__ sel,
                           const float* __restrict__ selw, int* __restrict__ basep,
                           int* __restrict__ rowmap, int* __restrict__ rowk,
                           float* __restrict__ roww) {
    __shared__ int lbase[NE];
    __shared__ int lfill[NE];
    const int t = threadIdx.x;
    if (t == 0) {
        int b = 0;
        for (int e = 0; e < NE; e++) { lbase[e] = b; basep[e] = b; b += counts[e]; lfill[e] = 0; }
    }
    __syncthreads();
    for (int n = t; n < NTOK; n += blockDim.x) {
#pragma unroll
        for (int k = 0; k < 2; k++) {
            int e = sel[n * 2 + k];
            int p = atomicAdd(&lfill[e], 1);
            int g = lbase[e] + p;
            rowmap[g] = n; rowk[g] = k; roww[g] = selw[n * 2 + k];
        }
    }
}

// ---------------- weight transpose+convert -> tile-contiguous layout (r18) ----------------
// Also zeroes `counts` (1 thread) and `out` (z==0 blocks, grid-stride): this
// kernel is first in stream order, so both are ready for router/gemm2; saves
// two hipMemsetAsync dispatches. Phase-B stores are non-temporal (172MB output
// doesn't fit L2 and is consumed only by later kernels).
__global__ void k_wt3(const float* __restrict__ w1, const float* __restrict__ w3,
                      const float* __restrict__ w2,
                      unsigned short* __restrict__ w1t, unsigned short* __restrict__ w3t,
                      unsigned short* __restrict__ w2t,
                      int* __restrict__ counts, float* __restrict__ out) {
    __shared__ unsigned int P[64 * 32];   // 8 KB pair layout: [n][32 k-pairs]
    const int z = blockIdx.z;
    const int t = threadIdx.x;

    if (z == 0) {
        if (blockIdx.x == 0 && t == 0) {
#pragma unroll
            for (int e = 0; e < NE; e++) counts[e] = 0;
        }
        // grid-stride zero of out: 2M floats = 524288 float4 over 896x256 threads
        f32x4* o4 = (f32x4*)out;
        const f32x4 zf = { 0.f, 0.f, 0.f, 0.f };
        for (unsigned int i = blockIdx.x * 256 + t; i < (NTOK * HD / 4); i += 896 * 256)
            o4[i] = zf;
    }

    int N, tx, ty;
    const float* src;
    unsigned short* dst;
    if (z < 16) {
        N = FD;
        const int e = z & 7;
        tx = blockIdx.x % (FD / 64); ty = blockIdx.x / (FD / 64);   // ftile, ktile
        src = (z < 8 ? w1 : w3) + (size_t)e * HD * FD;
        dst = (z < 8 ? w1t : w3t) + (size_t)e * HD * FD + ((size_t)tx * 16 + ty) * TSZ;
    } else {
        N = HD;
        const int e = z - 16;
        tx = blockIdx.x % (HD / 64); ty = blockIdx.x / (HD / 64);   // ntile, ktile
        src = w2 + (size_t)e * FD * HD;
        dst = w2t + (size_t)e * HD * FD + ((size_t)tx * 56 + ty) * TSZ;
    }
    src += (size_t)(ty * 64) * N + tx * 64;

    {
        const int rp = t >> 3;            // k-pair index 0..31
        const int c8 = t & 7;             // 8-col group
        const float* s0 = src + (size_t)(2 * rp) * N + c8 * 8;
        const float* s1 = s0 + N;
        float4 a0 = *(const float4*)(s0);
        float4 a1 = *(const float4*)(s0 + 4);
        float4 b0 = *(const float4*)(s1);
        float4 b1 = *(const float4*)(s1 + 4);
        float ev[8] = { a0.x, a0.y, a0.z, a0.w, a1.x, a1.y, a1.z, a1.w };
        float od[8] = { b0.x, b0.y, b0.z, b0.w, b1.x, b1.y, b1.z, b1.w };
#pragma unroll
        for (int j = 0; j < 8; j++) {
            const int n = c8 * 8 + j;
            unsigned int v = (unsigned int)f2bf(ev[j]) | ((unsigned int)f2bf(od[j]) << 16);
            P[n * 32 + (rp ^ ((n >> 3) << 2))] = v;
        }
    }
    __syncthreads();
    {
        const int n0 = t >> 3;            // 0..31
        const int q  = t & 7;             // k-octet 0..7
#pragma unroll
        for (int p = 0; p < 2; p++) {
            const int n = n0 + 32 * p;
            u32x4 v = *(const u32x4*)&P[n * 32 + 4 * (q ^ (n >> 3))];
            __builtin_nontemporal_store(v, (u32x4*)&dst[n * 64 + q * 8]);
        }
    }
}

// ---------------- GEMM1: 256 thr, 4 waves 2x2, wave tile 64x32 (r18) ----------------
__global__ __launch_bounds__(256, 2) void k_gemm1(
    const unsigned short* __restrict__ xb,
    const unsigned short* __restrict__ w1t, const unsigned short* __restrict__ w3t,
    const int* __restrict__ counts, const int* __restrict__ basep,
    const int* __restrict__ rowmap, unsigned short* __restrict__ act)
{
    const int e = blockIdx.z;
    const int nrows = counts[e];
    const int m0 = blockIdx.y * BM;
    if (m0 >= nrows) return;
    const int f0 = blockIdx.x * BN1;
    const int gbase = basep[e];

    __shared__ __align__(16) unsigned short At[2][BM][BK];
    __shared__ __align__(16) unsigned short B1[2][BN1][BK];
    __shared__ __align__(16) unsigned short B3[2][BN1][BK];

    const int t = threadIdx.x;
    const int lane = t & 63;
    const int w = t >> 6;                 // 0..3
    const int wrm = w >> 1, wnn = w & 1;  // 2x2 wave grid; wave tile 64 x 32
    const int lr = lane >> 3;
    const int so = ((lane & 7) ^ lr) * 8; // verified swizzle: chunk ^ (row&7)

    const unsigned short* asrc[4];
#pragma unroll
    for (int c = 0; c < 4; c++) {
        const int row = (w * 4 + c) * 8 + lr;
        const int tok = rowmap[gbase + min(m0 + row, nrows - 1)];
        asrc[c] = xb + (size_t)tok * HD + so;
    }
    const unsigned short* b1src[2];
    const unsigned short* b3src[2];
#pragma unroll
    for (int c = 0; c < 2; c++) {
        const int row = (w * 2 + c) * 8 + lr;
        const size_t tb = (size_t)e * HD * FD + ((size_t)blockIdx.x * 16) * TSZ + row * 64 + so;
        b1src[c] = w1t + tb;
        b3src[c] = w3t + tb;
    }

    f32x4 acc1[4][2], acc3[4][2];
#pragma unroll
    for (int i = 0; i < 4; i++)
#pragma unroll
        for (int j = 0; j < 2; j++) { acc1[i][j] = (f32x4)(0.f); acc3[i][j] = (f32x4)(0.f); }

    const int l15 = lane & 15;
    const int lhi = lane >> 4;
    const int rs = (l15 & 7) * 8;

    // prologue: stage k-tile 0 into buf 0 (8 loads/thread in flight)
#pragma unroll
    for (int c = 0; c < 4; c++) gl16(asrc[c], &At[0][(w * 4 + c) * 8][0]);
#pragma unroll
    for (int c = 0; c < 2; c++) {
        gl16(b1src[c], &B1[0][(w * 2 + c) * 8][0]);
        gl16(b3src[c], &B3[0][(w * 2 + c) * 8][0]);
    }

    for (int it = 0; it < NIT1; ++it) {
        const int cur = it & 1;
        if (it + 1 < NIT1) {
            const int kn = (it + 1) * BK;              // A offset (row-major xb)
            const size_t bt = (size_t)(it + 1) * TSZ;  // B offset (tile-contiguous)
#pragma unroll
            for (int c = 0; c < 4; c++) gl16(asrc[c] + kn, &At[cur ^ 1][(w * 4 + c) * 8][0]);
#pragma unroll
            for (int c = 0; c < 2; c++) {
                gl16(b1src[c] + bt, &B1[cur ^ 1][(w * 2 + c) * 8][0]);
                gl16(b3src[c] + bt, &B3[cur ^ 1][(w * 2 + c) * 8][0]);
            }
            asm volatile("s_waitcnt vmcnt(8)" ::: "memory");   // wait current tile only
        } else {
            asm volatile("s_waitcnt vmcnt(0)" ::: "memory");
        }
        __builtin_amdgcn_s_barrier();
#pragma unroll
        for (int kk = 0; kk < 2; kk++) {
            const int kc = (kk * 32 + lhi * 8) ^ rs;
            short8 af[4], b1f[2], b3f[2];
#pragma unroll
            for (int i = 0; i < 4; i++)
                af[i] = *(const short8*)&At[cur][wrm * 64 + i * 16 + l15][kc];
#pragma unroll
            for (int j = 0; j < 2; j++) {
                b1f[j] = *(const short8*)&B1[cur][wnn * 32 + j * 16 + l15][kc];
                b3f[j] = *(const short8*)&B3[cur][wnn * 32 + j * 16 + l15][kc];
            }
#pragma unroll
            for (int i = 0; i < 4; i++)
#pragma unroll
                for (int j = 0; j < 2; j++) {
                    acc1[i][j] = __builtin_amdgcn_mfma_f32_16x16x32_bf16(af[i], b1f[j], acc1[i][j], 0, 0, 0);
                    acc3[i][j] = __builtin_amdgcn_mfma_f32_16x16x32_bf16(af[i], b3f[j], acc3[i][j], 0, 0, 0);
                }
        }
        __builtin_amdgcn_s_barrier();
    }

    // epilogue: SwiGLU, bf16 act
    const int rbase = wrm * 64 + lhi * 4;
    const int cbase = f0 + wnn * 32 + l15;
#pragma unroll
    for (int i = 0; i < 4; i++) {
#pragma unroll
        for (int r = 0; r < 4; r++) {
            const int ml = rbase + i * 16 + r;
            if (m0 + ml < nrows) {
                const size_t rowoff = (size_t)(gbase + m0 + ml) * FD;
#pragma unroll
                for (int j = 0; j < 2; j++) {
                    float y1 = acc1[i][j][r];
                    float y3 = acc3[i][j][r];
                    float sv = (y1 / (1.f + __expf(-y1))) * y3;
                    act[rowoff + cbase + j * 16] = f2bf(sv);
                }
            }
        }
    }
}

// ---------------- GEMM2: BM2=64 x BN=128, wave tile 32x64, K-split x2 (r18) ----------------
__global__ __launch_bounds__(256, 4) void k_gemm2(
    const unsigned short* __restrict__ act,
    const unsigned short* __restrict__ w2t,
    const int* __restrict__ counts, const int* __restrict__ basep,
    const int* __restrict__ rowmap, const int* __restrict__ rowk,
    const float* __restrict__ roww, float* __restrict__ out)
{
    const int z = blockIdx.z;
    const int e = z >> 1, ks = z & 1;
    const int nrows = counts[e];
    const int m0 = blockIdx.y * BM2;
    if (m0 >= nrows) return;
    const int h0 = blockIdx.x * BN;
    const int gbase = basep[e];
    const int kbase = ks * KLEN2;

    __shared__ __align__(16) unsigned short At[2][BM2][BK];
    __shared__ __align__(16) unsigned short Bt[2][BN][BK];

    const int t = threadIdx.x;
    const int lane = t & 63;
    const int w = t >> 6;                 // 0..3
    const int wr2 = w >> 1, wn2 = w & 1;  // 2x2; wave tile 32 x 64
    const int lr = lane >> 3;
    const int so = ((lane & 7) ^ lr) * 8;

    const unsigned short* asrc[2];
#pragma unroll
    for (int c = 0; c < 2; c++) {
        const int row = (w * 2 + c) * 8 + lr;
        asrc[c] = act + ((size_t)gbase + min(m0 + row, nrows - 1)) * FD + so + kbase;
    }
    const unsigned short* bsrc[4];
#pragma unroll
    for (int c = 0; c < 4; c++) {
        const int row = (w * 4 + c) * 8 + lr;
        const int ntile = (h0 >> 6) + (row >> 6);
        bsrc[c] = w2t + (size_t)e * HD * FD + ((size_t)ntile * 56 + ks * 28) * TSZ
                + (row & 63) * 64 + so;
    }

    f32x4 acc[2][4];
#pragma unroll
    for (int i = 0; i < 2; i++)
#pragma unroll
        for (int j = 0; j < 4; j++) acc[i][j] = (f32x4)(0.f);

    const int l15 = lane & 15;
    const int lhi = lane >> 4;
    const int rs = (l15 & 7) * 8;

    // prologue: stage tile 0 into buf 0 (6 loads/thread)
#pragma unroll
    for (int c = 0; c < 2; c++) gl16(asrc[c], &At[0][(w * 2 + c) * 8][0]);
#pragma unroll
    for (int c = 0; c < 4; c++) gl16(bsrc[c], &Bt[0][(w * 4 + c) * 8][0]);

    for (int it = 0; it < NIT2; ++it) {
        const int cur = it & 1;
        if (it + 1 < NIT2) {
            const int kn = (it + 1) * BK;
            const size_t bt = (size_t)(it + 1) * TSZ;
#pragma unroll
            for (int c = 0; c < 2; c++) gl16(asrc[c] + kn, &At[cur ^ 1][(w * 2 + c) * 8][0]);
#pragma unroll
            for (int c = 0; c < 4; c++) gl16(bsrc[c] + bt, &Bt[cur ^ 1][(w * 4 + c) * 8][0]);
            asm volatile("s_waitcnt vmcnt(6)" ::: "memory");
        } else {
            asm volatile("s_waitcnt vmcnt(0)" ::: "memory");
        }
        __builtin_amdgcn_s_barrier();
#pragma unroll
        for (int kk = 0; kk < 2; kk++) {
            const int kc = (kk * 32 + lhi * 8) ^ rs;
            short8 af[2], bf[4];
#pragma unroll
            for (int i = 0; i < 2; i++)
                af[i] = *(const short8*)&At[cur][wr2 * 32 + i * 16 + l15][kc];
#pragma unroll
            for (int j = 0; j < 4; j++)
                bf[j] = *(const short8*)&Bt[cur][wn2 * 64 + j * 16 + l15][kc];
#pragma unroll
            for (int i = 0; i < 2; i++)
#pragma unroll
                for (int j = 0; j < 4; j++)
                    acc[i][j] = __builtin_amdgcn_mfma_f32_16x16x32_bf16(af[i], bf[j], acc[i][j], 0, 0, 0);
        }
        __builtin_amdgcn_s_barrier();
    }

    const int rbase = wr2 * 32 + lhi * 4;
    const int cbase = h0 + wn2 * 64 + l15;
#pragma unroll
    for (int i = 0; i < 2; i++) {
#pragma unroll
        for (int r = 0; r < 4; r++) {
            const int ml = rbase + i * 16 + r;
            if (m0 + ml < nrows) {
                const int grow = gbase + m0 + ml;
                const int tok = rowmap[grow];
                const float wv = roww[grow];
                float* op = out + (size_t)tok * HD + cbase;
#pragma unroll
                for (int j = 0; j < 4; j++)
                    atomicAdd(&op[j * 16], acc[i][j][r] * wv);
            }
        }
    }
}

extern "C" void kernel_launch(void* const* d_in, const int* in_sizes, int n_in,
                              void* d_out, int out_size, void* d_ws, size_t ws_size,
                              hipStream_t stream) {
    const float* x  = (const float*)d_in[0];
    const float* gw = (const float*)d_in[1];
    const float* w1 = (const float*)d_in[2];
    const float* w3 = (const float*)d_in[3];
    const float* w2 = (const float*)d_in[4];
    float* out = (float*)d_out;

    char* ws = (char*)d_ws;
    size_t off = 0;
    auto alloc = [&](size_t b) { char* p = ws + off; off += (b + 255) & ~(size_t)255; return p; };
    int*   sel    = (int*)  alloc((size_t)NTOK * 2 * 4);
    float* selw   = (float*)alloc((size_t)NTOK * 2 * 4);
    int*   counts = (int*)  alloc(NE * 4);
    int*   basep  = (int*)  alloc(NE * 4);
    int*   rowmap = (int*)  alloc((size_t)NTOK * 2 * 4);
    int*   rowk   = (int*)  alloc((size_t)NTOK * 2 * 4);
    float* roww   = (float*)alloc((size_t)NTOK * 2 * 4);
    unsigned short* xb  = (unsigned short*)alloc((size_t)NTOK * HD * 2);
    unsigned short* act = (unsigned short*)alloc((size_t)NTOK * 2 * FD * 2);
    unsigned short* w1t = (unsigned short*)alloc((size_t)NE * HD * FD * 2);
    unsigned short* w3t = (unsigned short*)alloc((size_t)NE * HD * FD * 2);
    unsigned short* w2t = (unsigned short*)alloc((size_t)NE * HD * FD * 2);

    // k_wt3 (first in stream) also zeroes counts + out -> no memset dispatches.
    k_wt3<<<dim3(896, 1, 24), 256, 0, stream>>>(w1, w3, w2, w1t, w3t, w2t, counts, out);
    k_router<<<NTOK / 4, 256, 0, stream>>>(x, gw, xb, sel, selw, counts);
    k_scanfill<<<1, 256, 0, stream>>>(counts, sel, selw, basep, rowmap, rowk, roww);
    k_gemm1<<<dim3(FD / BN1, NTOK / BM, NE), 256, 0, stream>>>(xb, w1t, w3t, counts, basep, rowmap, act);
    k_gemm2<<<dim3(HD / BN, NTOK / BM2, NE * KS2), 256, 0, stream>>>(act, w2t, counts, basep, rowmap, rowk, roww, out);
}